// Round 10
// baseline (246.403 us; speedup 1.0000x reference)
//
#include <hip/hip_runtime.h>
#include <math.h>

#define N_NODES 50000
#define N_EDGES 800000
#define N_GRAPHS 64
#define D_IN 128
#define HID 64
#define OUT_C 32
#define NEG 0.2f
#define BN_EPS 1e-5f
#define N_TILES 3125    // N_NODES / 16
#define N_BUCKETS 196   // bucket = dst >> 8
#define BIN_CHUNK 4096
#define BIN_NB 196      // ceil(N_EDGES / BIN_CHUNK)
#define GEMM1_NB 782    // ceil(N_TILES / 4)
#define BUCKET_CAP 5120 // mean 4082, sd ~64 -> 16 sigma margin
#define CAP_PAD 6144    // fixed col region per bucket
#define PHANTOM N_NODES // sentinel node: xl rows = 0, esd = -1e30 -> weight 0
#define AGG_NB 1024     // persistent agg blocks (4096 waves)
#define N_WAVES (AGG_NB * 4)

typedef __attribute__((ext_vector_type(8))) short short8;
typedef __attribute__((ext_vector_type(4))) float f32x4;

static __device__ inline unsigned short f2bf(float f) {
    unsigned u = __float_as_uint(f);
    u += 0x7FFF + ((u >> 16) & 1);
    return (unsigned short)(u >> 16);
}
static __device__ inline float bfus(unsigned short u) {
    return __uint_as_float((unsigned)u << 16);
}

// =============== K1: fused front (bin | gemm1 | misc), role by blockIdx ===============

__global__ void __launch_bounds__(256) k_front(
        const int* __restrict__ src, const int* __restrict__ dst,
        int* __restrict__ gcur, unsigned* __restrict__ ebuf,
        const float* __restrict__ x, const float* __restrict__ W1,
        const float* __restrict__ a_src1, const float* __restrict__ a_dst1,
        unsigned short* __restrict__ xl1b, float* __restrict__ esd1,
        unsigned short* __restrict__ xl2b, float* __restrict__ esd2,
        const int* __restrict__ batch, int* __restrict__ gstart,
        float* __restrict__ sp1, float* __restrict__ sp2) {
    __shared__ __align__(16) char smem[23616];
    int tid = threadIdx.x;
    int blk = blockIdx.x;

    if (blk < BIN_NB) {
        // ---- bin role: LDS-binned edge partition into ebuf (4B records) ----
        int* cnt = (int*)smem;
        int* lofs = cnt + 256;
        int* dstoff = lofs + 256;
        int* ws4 = dstoff + 256;
        unsigned* stage = (unsigned*)(ws4 + 4);
        unsigned char* stage_b = (unsigned char*)(stage + BIN_CHUNK);
        cnt[tid] = 0;
        __syncthreads();
        int e0 = blk * BIN_CHUNK;
        int ne = N_EDGES - e0; if (ne > BIN_CHUNK) ne = BIN_CHUNK;
        unsigned rec[16]; int bkt[16], lp[16];
        #pragma unroll
        for (int j = 0; j < 16; ++j) {
            int r = j * 256 + tid;
            if (r < ne) {
                int e = e0 + r;
                int s = src[e], d = dst[e];
                rec[j] = ((unsigned)s << 8) | (unsigned)(d & 255);
                bkt[j] = d >> 8;
                lp[j] = atomicAdd(&cnt[bkt[j]], 1);
            } else bkt[j] = -1;
        }
        __syncthreads();
        int v = cnt[tid];
        int lane = tid & 63, wid = tid >> 6;
        int incl = v;
        #pragma unroll
        for (int off = 1; off < 64; off <<= 1) {
            int t = __shfl_up(incl, off, 64);
            if (lane >= off) incl += t;
        }
        if (lane == 63) ws4[wid] = incl;
        __syncthreads();
        if (tid == 0) {
            int a = ws4[0];
            #pragma unroll
            for (int j = 1; j < 4; ++j) { a += ws4[j]; ws4[j] = a; }
        }
        __syncthreads();
        if (wid > 0) incl += ws4[wid - 1];
        lofs[tid] = incl - v;
        __syncthreads();
        #pragma unroll
        for (int j = 0; j < 16; ++j) {
            if (bkt[j] >= 0) {
                int idx = lofs[bkt[j]] + lp[j];
                stage[idx] = rec[j];
                stage_b[idx] = (unsigned char)bkt[j];
            }
        }
        if (tid < N_BUCKETS && cnt[tid] > 0) {
            int g = atomicAdd(&gcur[tid], cnt[tid]);
            dstoff[tid] = tid * BUCKET_CAP + g - lofs[tid];
        }
        __syncthreads();
        for (int i = tid; i < ne; i += 256) {
            int b = stage_b[i];
            ebuf[dstoff[b] + i] = stage[i];
        }
        return;
    }

    if (blk < BIN_NB + GEMM1_NB) {
        // ---- gemm1 role: xl1b = bf16(x@W1), esd1 = x@[W1 a_src1 | W1 a_dst1] ----
        typedef unsigned short WtRow[144];
        WtRow* Wt = (WtRow*)smem;   // [80][144]
        for (int i = tid; i < 80 * 128; i += 256) {
            int n = i >> 7, k = i & 127;
            float v;
            if (n < 64) v = W1[k * 64 + n];
            else if (n < 72) {
                int hh = (n - 64) & 3;
                const float* a = ((n - 64) < 4 ? a_src1 : a_dst1) + hh * 16;
                v = 0.f;
                #pragma unroll
                for (int c = 0; c < 16; ++c) v = fmaf(W1[k * 64 + hh * 16 + c], a[c], v);
            } else v = 0.f;
            Wt[n][k] = f2bf(v);
        }
        __syncthreads();
        int lane = tid & 63, wid = tid >> 6;
        int tile = (blk - BIN_NB) * 4 + wid;
        if (tile >= N_TILES) return;
        int m = lane & 15, kg = lane >> 4;
        int base = tile * 16;
        const float* xr = x + (size_t)(base + m) * D_IN + kg * 8;
        f32x4 acc[5];
        #pragma unroll
        for (int t = 0; t < 5; ++t) acc[t] = (f32x4){0.f, 0.f, 0.f, 0.f};
        #pragma unroll
        for (int s = 0; s < 4; ++s) {
            f32x4 p = ((const f32x4*)(xr + s * 32))[0];
            f32x4 q = ((const f32x4*)(xr + s * 32))[1];
            short8 a;
            a[0] = (short)f2bf(p[0]); a[1] = (short)f2bf(p[1]);
            a[2] = (short)f2bf(p[2]); a[3] = (short)f2bf(p[3]);
            a[4] = (short)f2bf(q[0]); a[5] = (short)f2bf(q[1]);
            a[6] = (short)f2bf(q[2]); a[7] = (short)f2bf(q[3]);
            #pragma unroll
            for (int t = 0; t < 5; ++t) {
                short8 b = *(const short8*)&Wt[t * 16 + m][s * 32 + kg * 8];
                acc[t] = __builtin_amdgcn_mfma_f32_16x16x32_bf16(a, b, acc[t], 0, 0, 0);
            }
        }
        #pragma unroll
        for (int r = 0; r < 4; ++r) {
            int node = base + kg * 4 + r;
            #pragma unroll
            for (int t = 0; t < 4; ++t)
                xl1b[(size_t)node * HID + t * 16 + m] = f2bf(acc[t][r]);
            if (m < 8) esd1[node * 8 + m] = acc[4][r];
        }
        return;
    }

    // ---- misc role (one block): gstart, phantoms, zero stats partials ----
    if (tid <= N_GRAPHS) {
        int g = tid;
        int lo = 0, hi = N_NODES;
        while (lo < hi) {
            int mid = (lo + hi) >> 1;
            if (batch[mid] < g) lo = mid + 1; else hi = mid;
        }
        gstart[g] = lo;
    }
    if (tid >= 128 && tid < 192) xl1b[(size_t)PHANTOM * HID + (tid - 128)] = 0;
    if (tid >= 192 && tid < 200) esd1[(size_t)PHANTOM * 8 + (tid - 192)] = -1e30f;
    if (tid >= 200 && tid < 232) xl2b[(size_t)PHANTOM * OUT_C + (tid - 200)] = 0;
    if (tid >= 232 && tid < 234) esd2[(size_t)PHANTOM * 2 + (tid - 232)] = -1e30f;
    for (int i = tid; i < 64 * 128; i += 256) sp1[i] = 0.f;
    for (int i = tid; i < 64 * 64; i += 256) sp2[i] = 0.f;
}

// =============== K2: merged CSR build (count + intra-bucket scan + fill) ===============

__global__ void __launch_bounds__(256) k_csr(
        const unsigned* __restrict__ ebuf, const int* __restrict__ gcur,
        int2* __restrict__ rowinfo, int* __restrict__ col) {
    __shared__ int lcnt[256], lofs[256], lcur[256];
    __shared__ int ws[4];
    int tid = threadIdx.x, b = blockIdx.x;
    lcnt[tid] = 0;
    __syncthreads();
    int ne = gcur[b];
    const unsigned* eb = ebuf + (size_t)b * BUCKET_CAP;
    for (int i = tid; i < ne; i += 256)
        atomicAdd(&lcnt[eb[i] & 255u], 1);
    __syncthreads();
    int raw = lcnt[tid];
    int v = (raw + 3) & ~3;
    int lane = tid & 63, wid = tid >> 6;
    int incl = v;
    #pragma unroll
    for (int off = 1; off < 64; off <<= 1) {
        int t = __shfl_up(incl, off, 64);
        if (lane >= off) incl += t;
    }
    if (lane == 63) ws[wid] = incl;
    __syncthreads();
    if (tid == 0) {
        int a = ws[0];
        #pragma unroll
        for (int j = 1; j < 4; ++j) { a += ws[j]; ws[j] = a; }
    }
    __syncthreads();
    if (wid > 0) incl += ws[wid - 1];
    int js = b * CAP_PAD + (incl - v);
    int node = b * 256 + tid;
    if (node < N_NODES) rowinfo[node] = make_int2(js, js + v);
    lofs[tid] = js;
    lcur[tid] = 0;
    __syncthreads();
    for (int i = tid; i < ne; i += 256) {
        unsigned e = eb[i];
        int li = e & 255u;
        int p = atomicAdd(&lcur[li], 1);
        col[lofs[li] + p] = (int)(e >> 8);
    }
    for (int j = raw; j < v; ++j) col[js + j] = PHANTOM;
}

// =============== K3: layer-1 agg — persistent waves; h1 stored bf16 ===============

__global__ void __launch_bounds__(256) k_agg1(
        const unsigned short* __restrict__ xl1b, const float* __restrict__ esd1,
        const int2* __restrict__ rowinfo, const int* __restrict__ col,
        const float* __restrict__ b1, unsigned short* __restrict__ h1b,
        float* __restrict__ sp1) {
    __shared__ float ps[64], pq[64];
    int tid = threadIdx.x;
    if (tid < 64) { ps[tid] = 0.f; pq[tid] = 0.f; }
    __syncthreads();
    int wid = tid >> 6, lane = tid & 63;
    int wave = blockIdx.x * 4 + wid;
    int h = lane >> 4;
    float bl = b1[lane];
    float s = 0.f, q = 0.f;                     // per-lane (=channel) BN partials
    for (int d = wave; d < N_NODES; d += N_WAVES) {
        float edh = esd1[d * 8 + 4 + h];
        float e0 = esd1[d * 8 + h] + edh;       // self loop
        float w0 = __expf(fmaxf(e0, NEG * e0));
        float acc = w0 * bfus(xl1b[(size_t)d * HID + lane]);
        float wsum = w0;
        int2 ri = rowinfo[d];
        int jb = __builtin_amdgcn_readfirstlane(ri.x);
        int je = __builtin_amdgcn_readfirstlane(ri.y);
        int4 ca = *(const int4*)(col + jb);      // slack-safe overread
        int4 cb = *(const int4*)(col + jb + 4);
        int j = jb;
        for (; j + 8 <= je; j += 8) {
            int4 na = *(const int4*)(col + j + 8);   // prefetch next (slack-safe)
            int4 nb = *(const int4*)(col + j + 12);
            float x0 = bfus(xl1b[(size_t)ca.x * HID + lane]);
            float x1 = bfus(xl1b[(size_t)ca.y * HID + lane]);
            float x2 = bfus(xl1b[(size_t)ca.z * HID + lane]);
            float x3 = bfus(xl1b[(size_t)ca.w * HID + lane]);
            float x4 = bfus(xl1b[(size_t)cb.x * HID + lane]);
            float x5 = bfus(xl1b[(size_t)cb.y * HID + lane]);
            float x6 = bfus(xl1b[(size_t)cb.z * HID + lane]);
            float x7 = bfus(xl1b[(size_t)cb.w * HID + lane]);
            float g0 = esd1[ca.x * 8 + h] + edh;
            float g1 = esd1[ca.y * 8 + h] + edh;
            float g2 = esd1[ca.z * 8 + h] + edh;
            float g3 = esd1[ca.w * 8 + h] + edh;
            float g4 = esd1[cb.x * 8 + h] + edh;
            float g5 = esd1[cb.y * 8 + h] + edh;
            float g6 = esd1[cb.z * 8 + h] + edh;
            float g7 = esd1[cb.w * 8 + h] + edh;
            float w_0 = __expf(fmaxf(g0, NEG * g0));
            float w_1 = __expf(fmaxf(g1, NEG * g1));
            float w_2 = __expf(fmaxf(g2, NEG * g2));
            float w_3 = __expf(fmaxf(g3, NEG * g3));
            float w_4 = __expf(fmaxf(g4, NEG * g4));
            float w_5 = __expf(fmaxf(g5, NEG * g5));
            float w_6 = __expf(fmaxf(g6, NEG * g6));
            float w_7 = __expf(fmaxf(g7, NEG * g7));
            acc = fmaf(w_0, x0, acc); acc = fmaf(w_1, x1, acc);
            acc = fmaf(w_2, x2, acc); acc = fmaf(w_3, x3, acc);
            acc = fmaf(w_4, x4, acc); acc = fmaf(w_5, x5, acc);
            acc = fmaf(w_6, x6, acc); acc = fmaf(w_7, x7, acc);
            wsum += (w_0 + w_1) + (w_2 + w_3) + (w_4 + w_5) + (w_6 + w_7);
            ca = na; cb = nb;
        }
        if (j < je) {   // 4-edge tail (rows padded to %4); ca holds it
            float x0 = bfus(xl1b[(size_t)ca.x * HID + lane]);
            float x1 = bfus(xl1b[(size_t)ca.y * HID + lane]);
            float x2 = bfus(xl1b[(size_t)ca.z * HID + lane]);
            float x3 = bfus(xl1b[(size_t)ca.w * HID + lane]);
            float g0 = esd1[ca.x * 8 + h] + edh;
            float g1 = esd1[ca.y * 8 + h] + edh;
            float g2 = esd1[ca.z * 8 + h] + edh;
            float g3 = esd1[ca.w * 8 + h] + edh;
            float w_0 = __expf(fmaxf(g0, NEG * g0));
            float w_1 = __expf(fmaxf(g1, NEG * g1));
            float w_2 = __expf(fmaxf(g2, NEG * g2));
            float w_3 = __expf(fmaxf(g3, NEG * g3));
            acc = fmaf(w_0, x0, acc); acc = fmaf(w_1, x1, acc);
            acc = fmaf(w_2, x2, acc); acc = fmaf(w_3, x3, acc);
            wsum += (w_0 + w_1) + (w_2 + w_3);
        }
        float r = acc / wsum + bl;
        h1b[(size_t)d * HID + lane] = f2bf(r);
        s += r;
        q = fmaf(r, r, q);
    }
    atomicAdd(&ps[lane], s);
    atomicAdd(&pq[lane], q);
    __syncthreads();
    int slot = (blockIdx.x & 63) * 128;
    if (tid < 64) atomicAdd(&sp1[slot + tid], ps[tid]);
    else if (tid < 128) atomicAdd(&sp1[slot + tid], pq[tid - 64]);
}

// =============== K4: layer-2 GEMM (bn1+relu fused; bf16 h1 input) ===============

__global__ void __launch_bounds__(256) k_gemm2(
        const unsigned short* __restrict__ h1b, const float* __restrict__ sp1,
        const float* __restrict__ g1, const float* __restrict__ be1,
        const float* __restrict__ W2, const float* __restrict__ a_src2,
        const float* __restrict__ a_dst2,
        unsigned short* __restrict__ xl2b, float* __restrict__ esd2) {
    __shared__ unsigned short Wt[48][80];
    __shared__ float A1s[64], B1s[64], red[128];
    int tid = threadIdx.x;
    for (int i = tid; i < 48 * 64; i += 256) {
        int n = i >> 6, k = i & 63;
        float v;
        if (n < 32) v = W2[k * 32 + n];
        else if (n < 34) {
            const float* a = (n == 32) ? a_src2 : a_dst2;
            v = 0.f;
            #pragma unroll
            for (int c = 0; c < 32; ++c) v = fmaf(W2[k * 32 + c], a[c], v);
        } else v = 0.f;
        Wt[n][k] = f2bf(v);
    }
    if (tid < 128) {
        float s = 0.f;
        for (int j = 0; j < 64; ++j) s += sp1[j * 128 + tid];
        red[tid] = s;
    }
    __syncthreads();
    if (tid < 64) {
        float mu = red[tid] * (1.f / N_NODES);
        float var = red[64 + tid] * (1.f / N_NODES) - mu * mu;
        float sc = g1[tid] * rsqrtf(var + BN_EPS);
        A1s[tid] = sc;
        B1s[tid] = be1[tid] - mu * sc;
    }
    __syncthreads();
    int lane = tid & 63, wid = tid >> 6;
    int tile = blockIdx.x * 4 + wid;
    if (tile >= N_TILES) return;
    int m = lane & 15, kg = lane >> 4;
    int base = tile * 16;
    const unsigned short* hr = h1b + (size_t)(base + m) * HID + kg * 8;
    f32x4 acc[3];
    #pragma unroll
    for (int t = 0; t < 3; ++t) acc[t] = (f32x4){0.f, 0.f, 0.f, 0.f};
    #pragma unroll
    for (int s = 0; s < 2; ++s) {
        int k0 = s * 32 + kg * 8;
        short8 hraw = *(const short8*)(hr + s * 32);
        short8 a;
        #pragma unroll
        for (int j = 0; j < 8; ++j) {
            float v = fmaf(bfus((unsigned short)hraw[j]), A1s[k0 + j], B1s[k0 + j]);
            a[j] = (short)f2bf(v > 0.f ? v : 0.f);
        }
        #pragma unroll
        for (int t = 0; t < 3; ++t) {
            short8 b = *(const short8*)&Wt[t * 16 + m][s * 32 + kg * 8];
            acc[t] = __builtin_amdgcn_mfma_f32_16x16x32_bf16(a, b, acc[t], 0, 0, 0);
        }
    }
    #pragma unroll
    for (int r = 0; r < 4; ++r) {
        int node = base + kg * 4 + r;
        #pragma unroll
        for (int t = 0; t < 2; ++t)
            xl2b[(size_t)node * OUT_C + t * 16 + m] = f2bf(acc[t][r]);
        if (m < 2) esd2[node * 2 + m] = acc[2][r];
    }
}

// =============== K5: layer-2 agg — persistent waves; h2 stored bf16 ===============

__global__ void __launch_bounds__(256) k_agg2(
        const unsigned short* __restrict__ xl2b, const float* __restrict__ esd2,
        const int2* __restrict__ rowinfo, const int* __restrict__ col,
        const float* __restrict__ b2, unsigned short* __restrict__ h2b,
        float* __restrict__ sp2) {
    __shared__ float ps[32], pq[32];
    int tid = threadIdx.x;
    if (tid < 32) { ps[tid] = 0.f; pq[tid] = 0.f; }
    __syncthreads();
    int wid = tid >> 6, lane = tid & 63;
    int wave = blockIdx.x * 4 + wid;
    int c2 = lane & 31, half = lane >> 5;
    float bl = b2[c2];
    float s = 0.f, q = 0.f;
    for (int d = wave; d < N_NODES; d += N_WAVES) {
        float edh = esd2[d * 2 + 1];
        float acc = 0.f, wsum = 0.f;
        if (half == 0) {   // self loop on half 0
            float e0 = esd2[d * 2] + edh;
            float w0 = __expf(fmaxf(e0, NEG * e0));
            acc = w0 * bfus(xl2b[(size_t)d * OUT_C + c2]);
            wsum = w0;
        }
        int2 ri = rowinfo[d];
        int jb = __builtin_amdgcn_readfirstlane(ri.x);
        int je = __builtin_amdgcn_readfirstlane(ri.y);
        int4 ca = *(const int4*)(col + jb);
        int4 cb = *(const int4*)(col + jb + 4);
        int j = jb;
        for (; j + 8 <= je; j += 8) {
            int4 na = *(const int4*)(col + j + 8);
            int4 nb = *(const int4*)(col + j + 12);
            int s0 = half ? ca.y : ca.x;
            int s1 = half ? ca.w : ca.z;
            int s2 = half ? cb.y : cb.x;
            int s3 = half ? cb.w : cb.z;
            float x0 = bfus(xl2b[(size_t)s0 * OUT_C + c2]);
            float x1 = bfus(xl2b[(size_t)s1 * OUT_C + c2]);
            float x2 = bfus(xl2b[(size_t)s2 * OUT_C + c2]);
            float x3 = bfus(xl2b[(size_t)s3 * OUT_C + c2]);
            float g0 = esd2[s0 * 2] + edh;
            float g1 = esd2[s1 * 2] + edh;
            float g2 = esd2[s2 * 2] + edh;
            float g3 = esd2[s3 * 2] + edh;
            float w_0 = __expf(fmaxf(g0, NEG * g0));
            float w_1 = __expf(fmaxf(g1, NEG * g1));
            float w_2 = __expf(fmaxf(g2, NEG * g2));
            float w_3 = __expf(fmaxf(g3, NEG * g3));
            acc = fmaf(w_0, x0, acc); acc = fmaf(w_1, x1, acc);
            acc = fmaf(w_2, x2, acc); acc = fmaf(w_3, x3, acc);
            wsum += (w_0 + w_1) + (w_2 + w_3);
            ca = na; cb = nb;
        }
        if (j < je) {   // 4-edge tail; ca holds it
            int s0 = half ? ca.y : ca.x;
            int s1 = half ? ca.w : ca.z;
            float x0 = bfus(xl2b[(size_t)s0 * OUT_C + c2]);
            float x1 = bfus(xl2b[(size_t)s1 * OUT_C + c2]);
            float g0 = esd2[s0 * 2] + edh;
            float g1 = esd2[s1 * 2] + edh;
            float w_0 = __expf(fmaxf(g0, NEG * g0));
            float w_1 = __expf(fmaxf(g1, NEG * g1));
            acc = fmaf(w_0, x0, acc); acc = fmaf(w_1, x1, acc);
            wsum += w_0 + w_1;
        }
        acc += __shfl_xor(acc, 32, 64);
        wsum += __shfl_xor(wsum, 32, 64);
        if (half == 0) {
            float r = acc / wsum + bl;
            h2b[(size_t)d * OUT_C + c2] = f2bf(r);
            s += r;
            q = fmaf(r, r, q);
        }
    }
    if (half == 0) {
        atomicAdd(&ps[c2], s);
        atomicAdd(&pq[c2], q);
    }
    __syncthreads();
    int slot = (blockIdx.x & 63) * 64;
    if (tid < 32) atomicAdd(&sp2[slot + tid], ps[tid]);
    else if (tid < 64) atomicAdd(&sp2[slot + tid], pq[tid - 32]);
}

// =============== K6: fused BN2-apply + pool partials (bf16 h2 input) ===============

__global__ void __launch_bounds__(256) k_bnpool(
        const unsigned short* __restrict__ h2b, const float* __restrict__ sp2,
        const float* __restrict__ g2, const float* __restrict__ be2,
        const int* __restrict__ gstart, float* __restrict__ out,
        float* __restrict__ pfeat) {
    __shared__ float A2[OUT_C], B2[OUT_C], red[64];
    int tid = threadIdx.x;
    if (tid < 64) {
        float s = 0.f;
        for (int j = 0; j < 64; ++j) s += sp2[j * 64 + tid];
        red[tid] = s;
    }
    __syncthreads();
    if (tid < 32) {
        float mu = red[tid] * (1.f / N_NODES);
        float var = red[32 + tid] * (1.f / N_NODES) - mu * mu;
        float sc = g2[tid] * rsqrtf(var + BN_EPS);
        A2[tid] = sc;
        B2[tid] = be2[tid] - mu * sc;
    }
    __syncthreads();
    int g = blockIdx.x >> 2, part = blockIdx.x & 3;
    int s = gstart[g], e = gstart[g + 1];
    int len = e - s;
    int qq = (len + 3) >> 2;
    int ps = s + part * qq;
    int pe = ps + qq; if (pe > e) pe = e;
    int c = tid & 31, r = tid >> 5;
    float sum = 0.f, mx = -INFINITY;
    for (int n = ps + r; n < pe; n += 8) {
        float v = fmaf(bfus(h2b[(size_t)n * OUT_C + c]), A2[c], B2[c]);
        out[(size_t)n * OUT_C + c] = v;
        sum += v;
        mx = fmaxf(mx, v);
    }
    __shared__ float lsum[256], lmax[256];
    lsum[tid] = sum;
    lmax[tid] = mx;
    __syncthreads();
    if (tid < 32) {
        float ts = 0.f, tm = -INFINITY;
        for (int rr = 0; rr < 8; ++rr) {
            ts += lsum[rr * 32 + c];
            tm = fmaxf(tm, lmax[rr * 32 + c]);
        }
        pfeat[blockIdx.x * 64 + c] = ts;
        pfeat[blockIdx.x * 64 + 32 + c] = tm;
    }
}

// =============== K7: MLP head (+pool combine) -> graph_emb ===============

__global__ void __launch_bounds__(256) k_mlp(
        const float* __restrict__ pfeat, const int* __restrict__ gstart,
        const float* __restrict__ fcW1, const float* __restrict__ fcb1,
        const float* __restrict__ fcW2, const float* __restrict__ fcb2,
        float* __restrict__ out) {
    __shared__ float gf[N_GRAPHS * 64];
    __shared__ float t1[N_GRAPHS * OUT_C];
    int tid = threadIdx.x;
    for (int i = tid; i < N_GRAPHS * 32; i += 256) {
        int g = i >> 5, c = i & 31;
        float sm = 0.f, mx = -INFINITY;
        #pragma unroll
        for (int p = 0; p < 4; ++p) {
            sm += pfeat[(g * 4 + p) * 64 + c];
            mx = fmaxf(mx, pfeat[(g * 4 + p) * 64 + 32 + c]);
        }
        int cnt = gstart[g + 1] - gstart[g];
        gf[g * 64 + c] = (cnt > 0) ? sm / (float)cnt : 0.f;
        gf[g * 64 + 32 + c] = (cnt > 0) ? mx : 0.f;
    }
    __syncthreads();
    for (int i = tid; i < N_GRAPHS * OUT_C; i += 256) {
        int g = i >> 5, j = i & 31;
        float a = fcb1[j];
        for (int k = 0; k < 64; ++k) a = fmaf(gf[g * 64 + k], fcW1[k * OUT_C + j], a);
        t1[i] = a > 0.f ? a : 0.f;
    }
    __syncthreads();
    for (int i = tid; i < N_GRAPHS * OUT_C; i += 256) {
        int g = i >> 5, oc = i & 31;
        float a = fcb2[oc];
        for (int k = 0; k < OUT_C; ++k) a = fmaf(t1[g * OUT_C + k], fcW2[k * OUT_C + oc], a);
        out[(size_t)N_NODES * OUT_C + g * OUT_C + oc] = a;
    }
}

// =============== launch ===============

extern "C" void kernel_launch(void* const* d_in, const int* in_sizes, int n_in,
                              void* d_out, int out_size, void* d_ws, size_t ws_size,
                              hipStream_t stream) {
    (void)in_sizes; (void)n_in; (void)out_size; (void)ws_size;
    const float* x      = (const float*)d_in[0];
    const int*   ei     = (const int*)d_in[1];
    const int*   batch  = (const int*)d_in[2];
    const float* W1     = (const float*)d_in[3];
    const float* a_src1 = (const float*)d_in[4];
    const float* a_dst1 = (const float*)d_in[5];
    const float* b1     = (const float*)d_in[6];
    const float* g1     = (const float*)d_in[7];
    const float* be1    = (const float*)d_in[8];
    const float* W2     = (const float*)d_in[9];
    const float* a_src2 = (const float*)d_in[10];
    const float* a_dst2 = (const float*)d_in[11];
    const float* b2     = (const float*)d_in[12];
    const float* g2     = (const float*)d_in[13];
    const float* be2    = (const float*)d_in[14];
    const float* fcW1   = (const float*)d_in[15];
    const float* fcb1   = (const float*)d_in[16];
    const float* fcW2   = (const float*)d_in[17];
    const float* fcb2   = (const float*)d_in[18];
    const int* srcv = ei;
    const int* dstv = ei + N_EDGES;
    float* out = (float*)d_out;

    char* w = (char*)d_ws;
    size_t o = 0;
    #define ALLOC(nbytes) (w + o); o = (o + (size_t)(nbytes) + 15) & ~(size_t)15
    int*   gcur      = (int*)ALLOC(N_BUCKETS * 4);
    size_t zero_bytes = o;                       // only gcur needs pre-zero
    float* sp1       = (float*)ALLOC(64 * 128 * 4);   // zeroed by k_front misc
    float* sp2       = (float*)ALLOC(64 * 64 * 4);    // zeroed by k_front misc
    int2*  rowinfo   = (int2*)ALLOC((size_t)N_NODES * 8);
    int*   gst       = (int*)ALLOC(66 * 4);
    int*   col       = (int*)ALLOC(((size_t)N_BUCKETS * CAP_PAD + 256) * 4);
    unsigned* ebuf   = (unsigned*)ALLOC((size_t)N_BUCKETS * BUCKET_CAP * 4);
    unsigned short* xl1b = (unsigned short*)ALLOC((size_t)(N_NODES + 1) * HID * 2);
    float* esd1      = (float*)ALLOC((size_t)(N_NODES + 1) * 8 * 4);
    unsigned short* h1b  = (unsigned short*)ALLOC((size_t)N_NODES * HID * 2);
    unsigned short* xl2b = (unsigned short*)ALLOC((size_t)(N_NODES + 1) * OUT_C * 2);
    float* esd2      = (float*)ALLOC((size_t)(N_NODES + 1) * 2 * 4);
    float* pfeat     = (float*)ALLOC(256 * 64 * 4);
    #undef ALLOC
    unsigned short* h2b = h1b;   // h1b dead after k_gemm2; h2b is N*32*2 <= N*64*2

    hipMemsetAsync(d_ws, 0, zero_bytes, stream);
    k_front <<<BIN_NB + GEMM1_NB + 1, 256, 0, stream>>>(
        srcv, dstv, gcur, ebuf, x, W1, a_src1, a_dst1,
        xl1b, esd1, xl2b, esd2, batch, gst, sp1, sp2);
    k_csr   <<<N_BUCKETS, 256, 0, stream>>>(ebuf, gcur, rowinfo, col);
    k_agg1  <<<AGG_NB, 256, 0, stream>>>(
        xl1b, esd1, rowinfo, col, b1, h1b, sp1);
    k_gemm2 <<<(N_TILES + 3) / 4, 256, 0, stream>>>(
        h1b, sp1, g1, be1, W2, a_src2, a_dst2, xl2b, esd2);
    k_agg2  <<<AGG_NB, 256, 0, stream>>>(
        xl2b, esd2, rowinfo, col, b2, h2b, sp2);
    k_bnpool<<<256, 256, 0, stream>>>(h2b, sp2, g2, be2, gst, out, pfeat);
    k_mlp   <<<1, 256, 0, stream>>>(pfeat, gst, fcW1, fcb1, fcW2, fcb2, out);
}